// Round 10
// baseline (236.392 us; speedup 1.0000x reference)
//
#include <hip/hip_runtime.h>
#include <hip/hip_bf16.h>
#include <math.h>

#define B_    32
#define L_    4096
#define UNITS 512
#define ROWS  (B_ * L_)          // 131072
#define PI_F  3.14159265358979323846f
#define ROWU  20                 // uints per 32-k LDS row (80 B pad: <=2-way bank alias)
#define HLOG2E 0.7213475204444817f   // 0.5*log2(e)
#define LOG2E  1.4426950408889634f
#define TLOG2E 2.8853900817779268f   // 2*log2(e)

typedef __attribute__((ext_vector_type(8))) short short8;
typedef __attribute__((ext_vector_type(4))) float f32x4;

__device__ inline float fexp2(float x) { return __builtin_amdgcn_exp2f(x); }
__device__ inline float frcp(float x)  { return __builtin_amdgcn_rcpf(x); }
__device__ inline float fsin1(float r) { return __builtin_amdgcn_sinf(r); }  // sin(2*pi*r)
__device__ inline float fcos1(float r) { return __builtin_amdgcn_cosf(r); }  // cos(2*pi*r)
__device__ inline float ftanh(float y) {
    float e = fexp2(y * TLOG2E);               // e^(2y)
    return 1.0f - 2.0f * frcp(e + 1.0f);
}

__device__ inline ushort f2bf(float f) {
    uint u = __float_as_uint(f);
    return (ushort)((u + 0x7fffu + ((u >> 16) & 1u)) >> 16);   // RNE
}
__device__ inline float bf2f(ushort h) { return __uint_as_float(((uint)h) << 16); }

// split two f32 into packed bf16 hi + packed bf16 lo (RNE both)
__device__ inline void split2(float f0, float f1, uint& hi, uint& lo) {
    __hip_bfloat162 h2 = __float22bfloat162_rn(make_float2(f0, f1));
    hi = *reinterpret_cast<uint*>(&h2);
    float h0 = __uint_as_float(hi << 16);
    float h1 = __uint_as_float(hi & 0xffff0000u);
    __hip_bfloat162 l2 = __float22bfloat162_rn(make_float2(f0 - h0, f1 - h1));
    lo = *reinterpret_cast<uint*>(&l2);
}

__device__ inline void onl(float& m, float& s, float m2, float s2) {
    float nm = fmaxf(m, m2);
    s = s * fexp2((m - nm) * LOG2E) + s2 * fexp2((m2 - nm) * LOG2E);
    m = nm;
}

// ---------------- workspace layout (bytes), total ~1.3 MB ----------------
#define OFF_WHT   ((size_t)0)                    // [128][512] bf16 hi (W^T, permuted cols)
#define OFF_WLT   (OFF_WHT + (size_t)131072)     // [128][512] bf16 lo
#define OFF_PSW   (OFF_WLT + (size_t)131072)     // [512] float2 psi weights
#define OFF_PRI   (OFF_PSW + (size_t)4096)       // [1024][64] float2 partial re/im
#define OFF_PMPHI (OFF_PRI + (size_t)524288)     // [1024][64] f32
#define OFF_PSPHI (OFF_PMPHI + (size_t)262144)
#define OFF_PMPSI (OFF_PSPHI + (size_t)262144)   // [1024]
#define OFF_PSPSI (OFF_PMPSI + (size_t)4096)

// K0 (verbatim R5): split weights into bf16 hi/lo, W^T [128][512] with column
// permutation pr=((n>>5)<<6)|(n&31) for phi_r col n, pr+32 for phi_theta.
__global__ void k0_pack(const float* __restrict__ psi_r, const float* __restrict__ psi_t,
                        const float* __restrict__ phi_r, const float* __restrict__ phi_t,
                        ushort* __restrict__ wht, ushort* __restrict__ wlt,
                        float2* __restrict__ psw) {
    const int k = blockIdx.x;     // 0..511
    const int n = threadIdx.x;    // 0..63
    const int pr = ((n >> 5) << 6) | (n & 31);
    const int pt = pr + 32;
    float w0 = phi_r[k * 64 + n];
    float w1 = phi_t[k * 64 + n];
    ushort h0 = f2bf(w0), h1 = f2bf(w1);
    wht[(size_t)pr * 512 + k] = h0;
    wht[(size_t)pt * 512 + k] = h1;
    wlt[(size_t)pr * 512 + k] = f2bf(w0 - bf2f(h0));
    wlt[(size_t)pt * 512 + k] = f2bf(w1 - bf2f(h1));
    if (n == 0) psw[k] = make_float2(psi_r[k], psi_t[k]);
}

// K1: z = x @ W via 3-pass split-bf16 MFMA. R5's proven 2-barrier structure:
//  - A: reg->LDS staged (transpose+convert during stage; split ONCE per element,
//    shared by both wc-halves), ROWU=20 pad. R5-verbatim addressing.
//  - B: fragments DIRECT from L2-resident wht/wlt (R6/R9-verified addressing,
//    same bits as the staged path) -> Bh/Bl LDS deleted.
//  - LDS total exactly 40960 B -> 4 blocks/CU (16 waves); launch_bounds(256,4).
//  - psi: R5-verbatim in-loop fmaf; stats computed in-register in the epilogue
//    (psr eliminated).
__global__ __launch_bounds__(256, 4) void k1_gemm(
        const float* __restrict__ x,
        const uint4* __restrict__ wht4, const uint4* __restrict__ wlt4,
        const float2* __restrict__ psw_g,
        const float* __restrict__ psi_tb_p, const float* __restrict__ phi_tb_p,
        float2* __restrict__ pri,
        float* __restrict__ pmphi, float* __restrict__ psphi,
        float* __restrict__ pmpsi, float* __restrict__ pspsi) {
    __shared__ __align__(16) uint smem[9216];       // 36864 B
    uint* const Ah = smem;                          // loop: [128][20] uints
    uint* const Al = smem + 2560;
    float2* const zuv = (float2*)smem;              // epilogue alias: [128][33] float2 = 33792 B
    float* const als    = (float*)(smem + 8448);    // [128]
    float* const bls    = (float*)(smem + 8576);    // [128]
    float* const stat_m = (float*)(smem + 8704);    // [4][32] flat
    float* const stat_s = (float*)(smem + 8832);
    float2* const red   = (float2*)(smem + 8960);   // [4][32] float2 = 1024 B (also psi tmp [0..3])
    __shared__ __align__(16) float2 pswl[512];      // 4096 B  -> grand total 40960 B

    const int t    = threadIdx.x;
    const int lane = t & 63;
    const int w = t >> 6, wr = w >> 1, wc = w & 1;
    const int r0 = blockIdx.x * 128;
    const int hi16 = lane >> 4, lo16 = lane & 15;

    ((float4*)pswl)[t] = ((const float4*)psw_g)[t];     // 4 KB

    f32x4 acc[4][4];
    #pragma unroll
    for (int i = 0; i < 4; ++i)
        #pragma unroll
        for (int j = 0; j < 4; ++j) acc[i][j] = (f32x4)0.f;

    float paccr[4] = {0.f, 0.f, 0.f, 0.f}, pacct[4] = {0.f, 0.f, 0.f, 0.f};
    const int xrow = t >> 3, xj = t & 7;   // x stage: rows (t>>3)+32p, float4 idx xj

    for (int kt = 0; kt < 512; kt += 32) {
        __syncthreads();    // prev iter's A-fragment reads done (covers pswl on iter 0)

        // ---- issue VMEM: x tile (HBM/L3) first, then B fragments (L2) ----
        float4 xv[4];
        #pragma unroll
        for (int p = 0; p < 4; ++p)
            xv[p] = *(const float4*)&x[(size_t)(r0 + xrow + 32 * p) * 512 + kt + xj * 4];
        uint4 vbh[4], vbl[4];
        #pragma unroll
        for (int nj = 0; nj < 4; ++nj) {
            const int row = (wc << 6) + (nj << 4) + lo16;           // packed W^T row
            const size_t gi = (size_t)row * 64 + (kt >> 3) + hi16;  // uint4 units
            vbh[nj] = wht4[gi];
            vbl[nj] = wlt4[gi];
        }

        // ---- psi partial dots (R5 verbatim) ----
        #pragma unroll
        for (int e = 0; e < 4; ++e) {
            float2 ww = pswl[kt + xj * 4 + e];
            #pragma unroll
            for (int p = 0; p < 4; ++p) {
                float xe = ((const float*)&xv[p])[e];
                paccr[p] = fmaf(xe, ww.x, paccr[p]);
                pacct[p] = fmaf(xe, ww.y, pacct[p]);
            }
        }
        // ---- split once + stage A (R5 verbatim) ----
        #pragma unroll
        for (int p = 0; p < 4; ++p) {
            const float* xe = (const float*)&xv[p];
            uint h0, l0, h1, l1;
            split2(xe[0], xe[1], h0, l0);
            split2(xe[2], xe[3], h1, l1);
            const int off = (xrow + 32 * p) * ROWU + xj * 2;
            *(uint2*)&Ah[off] = make_uint2(h0, h1);
            *(uint2*)&Al[off] = make_uint2(l0, l1);
        }
        __syncthreads();    // A tile visible

        // ---- MFMA phase: A frags per-mi from LDS, B from regs ----
        #pragma unroll
        for (int mi = 0; mi < 4; ++mi) {
            const int off = (wr * 64 + mi * 16 + lo16) * ROWU + hi16 * 4;
            short8 ahf = *(const short8*)&Ah[off];
            short8 alf = *(const short8*)&Al[off];
            #pragma unroll
            for (int nj = 0; nj < 4; ++nj) {
                short8 bhf = *reinterpret_cast<short8*>(&vbh[nj]);
                short8 blf = *reinterpret_cast<short8*>(&vbl[nj]);
                acc[mi][nj] = __builtin_amdgcn_mfma_f32_16x16x32_bf16(ahf, bhf, acc[mi][nj], 0, 0, 0);
                acc[mi][nj] = __builtin_amdgcn_mfma_f32_16x16x32_bf16(ahf, blf, acc[mi][nj], 0, 0, 0);
                acc[mi][nj] = __builtin_amdgcn_mfma_f32_16x16x32_bf16(alf, bhf, acc[mi][nj], 0, 0, 0);
            }
        }
    }

    // ================= epilogue =================
    // part 1: psi — butterfly the k-segment partials (all lanes end up holding
    // the row sums); amplitude-phase -> LDS; stats fully in-register.
    #pragma unroll
    for (int p = 0; p < 4; ++p) {
        #pragma unroll
        for (int off = 1; off <= 4; off <<= 1) {
            paccr[p] += __shfl_xor(paccr[p], off);
            pacct[p] += __shfl_xor(pacct[p], off);
        }
    }
    if (xj == 0) {
        const float psi_tb = psi_tb_p[0];
        #pragma unroll
        for (int p = 0; p < 4; ++p) {
            const int row = xrow + 32 * p;
            float zr = paccr[p], zt = pacct[p];
            float e = fexp2(zr * HLOG2E);                 // unnormalized amplitude
            float tt = ftanh(zt + psi_tb);
            float rev = (1.0f + tt) * 0.5f;               // psi angle in revolutions
            als[row] = e * fcos1(rev);
            bls[row] = e * fsin1(rev);
        }
    }
    // psi stats: online over this thread's 4 rows, then combine across the
    // 8 xrow groups (lane bits 3..5). xj-duplicates are not double-counted
    // (we never combine over bits 0..2).
    {
        float M = -3.4e38f, S = 0.f;
        #pragma unroll
        for (int p = 0; p < 4; ++p) {
            float zr = paccr[p];
            float nm = fmaxf(M, zr);
            S = S * fexp2((M - nm) * LOG2E) + fexp2((zr - nm) * LOG2E);
            M = nm;
        }
        #pragma unroll
        for (int off = 8; off <= 32; off <<= 1) {
            float m2 = __shfl_xor(M, off);
            float s2 = __shfl_xor(S, off);
            onl(M, S, m2, s2);
        }
        if (lane == 0) red[w] = make_float2(M, S);        // per-wave (32 rows)
    }
    __syncthreads();   // A-staging reads done -> zuv alias safe; als/bls/red visible
    if (t == 0) {
        float2 c0 = red[0];
        float M = c0.x, S = c0.y;
        #pragma unroll
        for (int wv = 1; wv < 4; ++wv) { float2 c = red[wv]; onl(M, S, c.x, c.y); }
        pmpsi[blockIdx.x] = M; pspsi[blockIdx.x] = S;
    }

    // part 2: two passes over nj; stage (u,v) in zuv, reduce with explicit
    // (row,state) indexing (R5-verified); q-pair pre-combined via shfl(32).
    const float phi_tb = phi_tb_p[0];
    #pragma unroll
    for (int nj = 0; nj < 2; ++nj) {
        float m = -3.4e38f, s = 0.f;
        #pragma unroll
        for (int mi = 0; mi < 4; ++mi) {
            const int rl = wr * 64 + mi * 16 + hi16 * 4;
            #pragma unroll
            for (int r = 0; r < 4; ++r) {
                float zr = acc[mi][nj][r];                // phi_r col (wc*32 + nj*16 + lo16)
                float zt = acc[mi][nj + 2][r];            // matching phi_theta col
                float eh = fexp2(zr * HLOG2E);
                float tt = ftanh(zt + phi_tb);
                float rev = -(1.0f + PI_F * tt) * 0.5f;
                rev = rev - floorf(rev);
                float u = eh * fcos1(rev), v = eh * fsin1(rev);
                zuv[(rl + r) * 33 + wc * 16 + lo16] = make_float2(u, v);
                float nm = fmaxf(m, zr);
                s = s * fexp2((m - nm) * LOG2E) + fexp2((zr - nm) * LOG2E);
                m = nm;
            }
        }
        #pragma unroll
        for (int off = 16; off <= 32; off <<= 1) {
            float m2 = __shfl_xor(m, off);
            float s2 = __shfl_xor(s, off);
            onl(m, s, m2, s2);
        }
        if (lane < 16) { stat_m[w * 32 + nj * 16 + lo16] = m; stat_s[w * 32 + nj * 16 + lo16] = s; }
        __syncthreads();

        {
            const int slot = t & 31, q = t >> 5;
            float re = 0.f, im = 0.f;
            #pragma unroll
            for (int i = 0; i < 16; ++i) {
                const int row = q + 8 * i;
                float2 uvv = zuv[row * 33 + slot];
                float a = als[row], b2 = bls[row];
                re = fmaf(a, uvv.x, fmaf(b2, uvv.y, re));   // cos(A-B)
                im = fmaf(b2, uvv.x, fmaf(-a, uvv.y, im));  // sin(A-B)
            }
            re += __shfl_xor(re, 32);                       // combine q-pair in-wave
            im += __shfl_xor(im, 32);
            if (lane < 32) red[w * 32 + slot] = make_float2(re, im);
        }
        __syncthreads();
        if (t < 32) {
            float re = 0.f, im = 0.f;
            #pragma unroll
            for (int wv = 0; wv < 4; ++wv) { re += red[wv * 32 + t].x; im += red[wv * 32 + t].y; }
            const int state = ((t >> 4) << 5) | (nj << 4) | (t & 15);
            pri[(size_t)blockIdx.x * 64 + state] = make_float2(re, im);
        }
        __syncthreads();   // before next pass overwrites zuv/red
    }

    // part 3: combine per-wave phi stats -> per-block partials
    if (t < 64) {
        const int wcn = t >> 5, nloc = t & 31;            // state n == t
        float M = stat_m[wcn * 32 + nloc], S = stat_s[wcn * 32 + nloc];
        onl(M, S, stat_m[(wcn + 2) * 32 + nloc], stat_s[(wcn + 2) * 32 + nloc]);
        pmphi[(size_t)blockIdx.x * 64 + t] = M;
        psphi[(size_t)blockIdx.x * 64 + t] = S;
    }
}

// K5: per batch: combine 32 block partials -> scales -> collapse -> out GEMM
__global__ __launch_bounds__(512) void k5_out(
        const float2* __restrict__ pri,
        const float* __restrict__ pmphi, const float* __restrict__ psphi,
        const float* __restrict__ pmpsi, const float* __restrict__ pspsi,
        const float* __restrict__ Smat, const float* __restrict__ sb_p,
        float* __restrict__ out) {
    const int b = blockIdx.x, t = threadIdx.x;
    __shared__ float cls[64];
    __shared__ float spsi_s;
    float sph = 0.f, re = 0.f, im = 0.f;
    if (t < 64) {
        float M = -3.4e38f, S = 0.f;
        for (int ch = 0; ch < 32; ++ch)
            onl(M, S, pmphi[(size_t)(b * 32 + ch) * 64 + t], psphi[(size_t)(b * 32 + ch) * 64 + t]);
        sph = fexp2(-M * HLOG2E) / sqrtf(S);              // 1/sqrt(sum exp(z))
        for (int ch = 0; ch < 32; ++ch) {
            float2 p = pri[(size_t)(b * 32 + ch) * 64 + t];
            re += p.x; im += p.y;
        }
    } else if (t == 64) {
        float M = -3.4e38f, S = 0.f;
        for (int ch = 0; ch < 32; ++ch)
            onl(M, S, pmpsi[b * 32 + ch], pspsi[b * 32 + ch]);
        spsi_s = fexp2(-M * HLOG2E) / sqrtf(S);
    }
    __syncthreads();
    if (t < 64) {
        float sc = spsi_s * sph;
        cls[t] = sc * sc * (re * re + im * im);
    }
    __syncthreads();
    float acc = sb_p[0];
    #pragma unroll 8
    for (int n = 0; n < 64; ++n) acc = fmaf(cls[n], Smat[n * UNITS + t], acc);
    out[(size_t)b * UNITS + t] = acc;
}

extern "C" void kernel_launch(void* const* d_in, const int* in_sizes, int n_in,
                              void* d_out, int out_size, void* d_ws, size_t ws_size,
                              hipStream_t stream) {
    const float* x      = (const float*)d_in[0];
    const float* psi_r  = (const float*)d_in[1];
    const float* psi_t  = (const float*)d_in[2];
    const float* psi_tb = (const float*)d_in[3];
    const float* phi_r  = (const float*)d_in[4];
    const float* phi_t  = (const float*)d_in[5];
    const float* phi_tb = (const float*)d_in[6];
    const float* Smat   = (const float*)d_in[7];
    const float* sb     = (const float*)d_in[8];
    float* out = (float*)d_out;

    char* ws = (char*)d_ws;
    ushort* wht  = (ushort*)(ws + OFF_WHT);
    ushort* wlt  = (ushort*)(ws + OFF_WLT);
    float2* psw  = (float2*)(ws + OFF_PSW);
    float2* pri  = (float2*)(ws + OFF_PRI);
    float* pmphi = (float*)(ws + OFF_PMPHI);
    float* psphi = (float*)(ws + OFF_PSPHI);
    float* pmpsi = (float*)(ws + OFF_PMPSI);
    float* pspsi = (float*)(ws + OFF_PSPSI);

    k0_pack<<<512, 64, 0, stream>>>(psi_r, psi_t, phi_r, phi_t, wht, wlt, psw);
    k1_gemm<<<ROWS / 128, 256, 0, stream>>>(x, (const uint4*)wht, (const uint4*)wlt, psw,
                                            psi_tb, phi_tb, pri, pmphi, psphi, pmpsi, pspsi);
    k5_out<<<B_, 512, 0, stream>>>(pri, pmphi, psphi, pmpsi, pspsi, Smat, sb, out);
}

// Round 12
// 93.351 us; speedup vs baseline: 2.5323x; 2.5323x over previous
//
#include <hip/hip_runtime.h>
#include <hip/hip_bf16.h>
#include <math.h>

#define B_    32
#define L_    4096
#define UNITS 512
#define ROWS  (B_ * L_)          // 131072
#define PI_F  3.14159265358979323846f
#define ROWU  20                 // uints per 32-k LDS row (80 B pad: <=2-way bank alias)
#define HLOG2E 0.7213475204444817f   // 0.5*log2(e)
#define LOG2E  1.4426950408889634f
#define TLOG2E 2.8853900817779268f   // 2*log2(e)

typedef __attribute__((ext_vector_type(8))) short short8;
typedef __attribute__((ext_vector_type(4))) float f32x4;

__device__ inline float fexp2(float x) { return __builtin_amdgcn_exp2f(x); }
__device__ inline float frcp(float x)  { return __builtin_amdgcn_rcpf(x); }
__device__ inline float fsin1(float r) { return __builtin_amdgcn_sinf(r); }  // sin(2*pi*r)
__device__ inline float fcos1(float r) { return __builtin_amdgcn_cosf(r); }  // cos(2*pi*r)
__device__ inline float ftanh(float y) {
    float e = fexp2(y * TLOG2E);               // e^(2y)
    return 1.0f - 2.0f * frcp(e + 1.0f);
}

__device__ inline ushort f2bf(float f) {
    uint u = __float_as_uint(f);
    return (ushort)((u + 0x7fffu + ((u >> 16) & 1u)) >> 16);   // RNE
}
__device__ inline float bf2f(ushort h) { return __uint_as_float(((uint)h) << 16); }

// split two f32 into packed bf16 hi + packed bf16 lo (RNE both)
__device__ inline void split2(float f0, float f1, uint& hi, uint& lo) {
    __hip_bfloat162 h2 = __float22bfloat162_rn(make_float2(f0, f1));
    hi = *reinterpret_cast<uint*>(&h2);
    float h0 = __uint_as_float(hi << 16);
    float h1 = __uint_as_float(hi & 0xffff0000u);
    __hip_bfloat162 l2 = __float22bfloat162_rn(make_float2(f0 - h0, f1 - h1));
    lo = *reinterpret_cast<uint*>(&l2);
}

__device__ inline void onl(float& m, float& s, float m2, float s2) {
    float nm = fmaxf(m, m2);
    s = s * fexp2((m - nm) * LOG2E) + s2 * fexp2((m2 - nm) * LOG2E);
    m = nm;
}

// ---------------- workspace layout (bytes), total ~1.3 MB ----------------
#define OFF_WHT   ((size_t)0)                    // [128][512] bf16 hi (W^T, permuted cols)
#define OFF_WLT   (OFF_WHT + (size_t)131072)     // [128][512] bf16 lo
#define OFF_PSW   (OFF_WLT + (size_t)131072)     // [512] float2 psi weights
#define OFF_PRI   (OFF_PSW + (size_t)4096)       // [1024][64] float2 partial re/im
#define OFF_PMPHI (OFF_PRI + (size_t)524288)     // [1024][64] f32
#define OFF_PSPHI (OFF_PMPHI + (size_t)262144)
#define OFF_PMPSI (OFF_PSPHI + (size_t)262144)   // [1024]
#define OFF_PSPSI (OFF_PMPSI + (size_t)4096)

// K0 (verbatim R5, battle-tested): split weights into bf16 hi/lo, W^T [128][512]
// with column permutation: packed col for phi_r col n is pr=((n>>5)<<6)|(n&31),
// for phi_theta col n it is pr+32 -> each wave's 64 packed cols = 32 r-cols +
// their matching 32 t-cols.
__global__ void k0_pack(const float* __restrict__ psi_r, const float* __restrict__ psi_t,
                        const float* __restrict__ phi_r, const float* __restrict__ phi_t,
                        ushort* __restrict__ wht, ushort* __restrict__ wlt,
                        float2* __restrict__ psw) {
    const int k = blockIdx.x;     // 0..511
    const int n = threadIdx.x;    // 0..63
    const int pr = ((n >> 5) << 6) | (n & 31);
    const int pt = pr + 32;
    float w0 = phi_r[k * 64 + n];
    float w1 = phi_t[k * 64 + n];
    ushort h0 = f2bf(w0), h1 = f2bf(w1);
    wht[(size_t)pr * 512 + k] = h0;
    wht[(size_t)pt * 512 + k] = h1;
    wlt[(size_t)pr * 512 + k] = f2bf(w0 - bf2f(h0));
    wlt[(size_t)pt * 512 + k] = f2bf(w1 - bf2f(h1));
    if (n == 0) psw[k] = make_float2(psi_r[k], psi_t[k]);
}

// K1: z = x @ W via 3-pass split-bf16 MFMA (A and B LDS-staged, R2/R3-verified
// main loop). Fused epilogue: psi amplitude-phase per row; phi (u,v) staged
// through an LDS tile (reusing dead A/B staging LDS) and reduced with explicit
// (row,state) indexing -> partial re/im per block; softmax partials fused.
__global__ __launch_bounds__(256) void k1_gemm(
        const float* __restrict__ x,
        const uint* __restrict__ wht, const uint* __restrict__ wlt,
        const float2* __restrict__ psw_g,
        const float* __restrict__ psi_tb_p, const float* __restrict__ phi_tb_p,
        float2* __restrict__ pri,
        float* __restrict__ pmphi, float* __restrict__ psphi,
        float* __restrict__ pmpsi, float* __restrict__ pspsi) {
    __shared__ __align__(16) uint smem4[4 * 2560];      // Ah|Al|Bh|Bl, 40960 B
    uint* const Ah = smem4;
    uint* const Al = smem4 + 2560;
    uint* const Bh = smem4 + 5120;
    uint* const Bl = smem4 + 7680;
    float2* const zuv = (float2*)smem4;                 // epilogue alias: [128][33] pairs (33792 B)
    __shared__ __align__(16) float2 pswl[512];          // 4096 B
    __shared__ float als[128], bls[128], psr[128];
    __shared__ float stat_m[4][32], stat_s[4][32];
    __shared__ float2 red[8][32];

    const int t    = threadIdx.x;
    const int lane = t & 63;
    const int w = t >> 6, wr = w >> 1, wc = w & 1;
    const int r0 = blockIdx.x * 128;
    const int hi16 = lane >> 4, lo16 = lane & 15;

    ((float4*)pswl)[t] = ((const float4*)psw_g)[t];     // 4 KB

    f32x4 acc[4][4];
    #pragma unroll
    for (int i = 0; i < 4; ++i)
        #pragma unroll
        for (int j = 0; j < 4; ++j) acc[i][j] = (f32x4)0.f;

    float paccr[4] = {0.f, 0.f, 0.f, 0.f}, pacct[4] = {0.f, 0.f, 0.f, 0.f};
    const int xrow = t >> 3, xj = t & 7;   // x stage: rows (t>>3)+32p, float4 idx xj
    const int wn = t >> 2, jw = t & 3;     // W stage: rows (t>>2)+64p, uint4 idx jw

    for (int kt = 0; kt < 512; kt += 32) {
        __syncthreads();    // prev iter's fragment reads done (also covers pswl on iter 0)
        // ---- stage A (x -> bf16 hi/lo in LDS) + psi partial dots ----
        float4 xv[4];
        #pragma unroll
        for (int p = 0; p < 4; ++p)
            xv[p] = *(const float4*)&x[(size_t)(r0 + xrow + 32 * p) * 512 + kt + xj * 4];
        #pragma unroll
        for (int e = 0; e < 4; ++e) {
            float2 ww = pswl[kt + xj * 4 + e];
            #pragma unroll
            for (int p = 0; p < 4; ++p) {
                float xe = ((const float*)&xv[p])[e];
                paccr[p] = fmaf(xe, ww.x, paccr[p]);
                pacct[p] = fmaf(xe, ww.y, pacct[p]);
            }
        }
        #pragma unroll
        for (int p = 0; p < 4; ++p) {
            const float* xe = (const float*)&xv[p];
            uint h0, l0, h1, l1;
            split2(xe[0], xe[1], h0, l0);
            split2(xe[2], xe[3], h1, l1);
            const int off = (xrow + 32 * p) * ROWU + xj * 2;
            *(uint2*)&Ah[off] = make_uint2(h0, h1);
            *(uint2*)&Al[off] = make_uint2(l0, l1);
        }
        // ---- stage B (row-major W^T from ws, R2/R3-verified) ----
        #pragma unroll
        for (int p = 0; p < 2; ++p) {
            const int n = wn + 64 * p;
            const size_t gi = (size_t)n * 256 + (kt >> 1) + jw * 4;
            uint4 vh = *(const uint4*)&wht[gi];
            uint4 vl = *(const uint4*)&wlt[gi];
            *(uint4*)&Bh[n * ROWU + jw * 4] = vh;
            *(uint4*)&Bl[n * ROWU + jw * 4] = vl;
        }
        __syncthreads();

        // ---- MFMA phase (R2/R3-verified fragment reads) ----
        short8 ahf[4], alf[4];
        #pragma unroll
        for (int mi = 0; mi < 4; ++mi) {
            const int off = (wr * 64 + mi * 16 + lo16) * ROWU + hi16 * 4;
            ahf[mi] = *(const short8*)&Ah[off];
            alf[mi] = *(const short8*)&Al[off];
        }
        #pragma unroll
        for (int nj = 0; nj < 4; ++nj) {
            const int off = (wc * 64 + nj * 16 + lo16) * ROWU + hi16 * 4;
            short8 bhf = *(const short8*)&Bh[off];
            short8 blf = *(const short8*)&Bl[off];
            #pragma unroll
            for (int mi = 0; mi < 4; ++mi) {
                acc[mi][nj] = __builtin_amdgcn_mfma_f32_16x16x32_bf16(ahf[mi], bhf, acc[mi][nj], 0, 0, 0);
                acc[mi][nj] = __builtin_amdgcn_mfma_f32_16x16x32_bf16(ahf[mi], blf, acc[mi][nj], 0, 0, 0);
                acc[mi][nj] = __builtin_amdgcn_mfma_f32_16x16x32_bf16(alf[mi], bhf, acc[mi][nj], 0, 0, 0);
            }
        }
    }

    // ================= epilogue =================
    // part 1: psi — reduce 8 k-segment partials per row; amplitude-phase -> LDS
    #pragma unroll
    for (int p = 0; p < 4; ++p) {
        #pragma unroll
        for (int off = 1; off <= 4; off <<= 1) {
            paccr[p] += __shfl_xor(paccr[p], off);
            pacct[p] += __shfl_xor(pacct[p], off);
        }
    }
    if (xj == 0) {
        const float psi_tb = psi_tb_p[0];
        #pragma unroll
        for (int p = 0; p < 4; ++p) {
            const int row = xrow + 32 * p;
            float zr = paccr[p], zt = pacct[p];
            float e = fexp2(zr * HLOG2E);                 // unnormalized amplitude
            float tt = ftanh(zt + psi_tb);
            float rev = (1.0f + tt) * 0.5f;               // psi angle in revolutions
            als[row] = e * fcos1(rev);
            bls[row] = e * fsin1(rev);
            psr[row] = zr;
        }
    }
    __syncthreads();   // MFMA reads of smem4 done -> safe to alias as zuv; als/bls/psr visible

    // part 2: two passes over nj; each pass stages (u,v) for 32 states in LDS,
    // then reduces over rows with explicit (row, state) indexing.
    const float phi_tb = phi_tb_p[0];
    #pragma unroll
    for (int nj = 0; nj < 2; ++nj) {
        // (a) compute u,v; write to zuv; online softmax stats on z_r
        float m = -3.4e38f, s = 0.f;
        #pragma unroll
        for (int mi = 0; mi < 4; ++mi) {
            #pragma unroll
            for (int r = 0; r < 4; ++r) {
                float zr = acc[mi][nj][r];                // phi_r col (wc*32 + nj*16 + lo16)
                float zt = acc[mi][nj + 2][r];            // matching phi_theta col
                float eh = fexp2(zr * HLOG2E);
                float tt = ftanh(zt + phi_tb);
                float rev = -(1.0f + PI_F * tt) * 0.5f;
                rev = rev - floorf(rev);
                float u = eh * fcos1(rev), v = eh * fsin1(rev);
                const int row = wr * 64 + mi * 16 + hi16 * 4 + r;
                zuv[row * 33 + wc * 16 + lo16] = make_float2(u, v);
                float nm = fmaxf(m, zr);
                s = s * fexp2((m - nm) * LOG2E) + fexp2((zr - nm) * LOG2E);
                m = nm;
            }
        }
        #pragma unroll
        for (int off = 16; off <= 32; off <<= 1) {
            float m2 = __shfl_xor(m, off);
            float s2 = __shfl_xor(s, off);
            onl(m, s, m2, s2);
        }
        if (lane < 16) { stat_m[w][nj * 16 + lo16] = m; stat_s[w][nj * 16 + lo16] = s; }
        __syncthreads();

        // (b) layout-free reduction: slot = wc*16+lo16 column of zuv
        {
            const int slot = t & 31, q = t >> 5;
            float re = 0.f, im = 0.f;
            #pragma unroll
            for (int i = 0; i < 16; ++i) {
                const int row = q + 8 * i;
                float2 uvv = zuv[row * 33 + slot];
                float a = als[row], b2 = bls[row];
                re = fmaf(a, uvv.x, fmaf(b2, uvv.y, re));   // cos(A-B) identity
                im = fmaf(b2, uvv.x, fmaf(-a, uvv.y, im));  // sin(A-B) identity
            }
            red[q][slot] = make_float2(re, im);
        }
        __syncthreads();
        if (t < 32) {
            float re = 0.f, im = 0.f;
            #pragma unroll
            for (int q = 0; q < 8; ++q) { re += red[q][t].x; im += red[q][t].y; }
            const int state = ((t >> 4) << 5) | (nj << 4) | (t & 15);
            pri[(size_t)blockIdx.x * 64 + state] = make_float2(re, im);
        }
        __syncthreads();   // before next pass overwrites zuv/red
    }

    // part 3: combine per-wave stats -> per-block partials (verbatim R3/R4)
    if (t < 64) {
        const int wcn = t >> 5, nloc = t & 31;            // state n == t
        float M = stat_m[wcn][nloc], S = stat_s[wcn][nloc];
        onl(M, S, stat_m[wcn + 2][nloc], stat_s[wcn + 2][nloc]);
        pmphi[(size_t)blockIdx.x * 64 + t] = M;
        psphi[(size_t)blockIdx.x * 64 + t] = S;
    } else if (t < 128) {
        const int i = t - 64;
        float a = psr[i], bb = psr[i + 64];
        float M = fmaxf(a, bb);
        float S = fexp2((a - M) * LOG2E) + fexp2((bb - M) * LOG2E);
        #pragma unroll
        for (int off = 1; off <= 32; off <<= 1) {
            float m2 = __shfl_xor(M, off);
            float s2 = __shfl_xor(S, off);
            onl(M, S, m2, s2);
        }
        if (i == 0) { pmpsi[blockIdx.x] = M; pspsi[blockIdx.x] = S; }
    }
}

// K5: per batch: combine 32 block partials -> scales -> collapse -> out GEMM
__global__ __launch_bounds__(512) void k5_out(
        const float2* __restrict__ pri,
        const float* __restrict__ pmphi, const float* __restrict__ psphi,
        const float* __restrict__ pmpsi, const float* __restrict__ pspsi,
        const float* __restrict__ Smat, const float* __restrict__ sb_p,
        float* __restrict__ out) {
    const int b = blockIdx.x, t = threadIdx.x;
    __shared__ float cls[64];
    __shared__ float spsi_s;
    float sph = 0.f, re = 0.f, im = 0.f;
    if (t < 64) {
        float M = -3.4e38f, S = 0.f;
        for (int ch = 0; ch < 32; ++ch)
            onl(M, S, pmphi[(size_t)(b * 32 + ch) * 64 + t], psphi[(size_t)(b * 32 + ch) * 64 + t]);
        sph = fexp2(-M * HLOG2E) / sqrtf(S);              // exp(-M/2)/sqrt(sum exp(z-M)) = 1/sqrt(sum exp(z))
        for (int ch = 0; ch < 32; ++ch) {
            float2 p = pri[(size_t)(b * 32 + ch) * 64 + t];
            re += p.x; im += p.y;
        }
    } else if (t == 64) {
        float M = -3.4e38f, S = 0.f;
        for (int ch = 0; ch < 32; ++ch)
            onl(M, S, pmpsi[b * 32 + ch], pspsi[b * 32 + ch]);
        spsi_s = fexp2(-M * HLOG2E) / sqrtf(S);
    }
    __syncthreads();
    if (t < 64) {
        float sc = spsi_s * sph;
        cls[t] = sc * sc * (re * re + im * im);
    }
    __syncthreads();
    float acc = sb_p[0];
    #pragma unroll 8
    for (int n = 0; n < 64; ++n) acc = fmaf(cls[n], Smat[n * UNITS + t], acc);
    out[(size_t)b * UNITS + t] = acc;
}

extern "C" void kernel_launch(void* const* d_in, const int* in_sizes, int n_in,
                              void* d_out, int out_size, void* d_ws, size_t ws_size,
                              hipStream_t stream) {
    const float* x      = (const float*)d_in[0];
    const float* psi_r  = (const float*)d_in[1];
    const float* psi_t  = (const float*)d_in[2];
    const float* psi_tb = (const float*)d_in[3];
    const float* phi_r  = (const float*)d_in[4];
    const float* phi_t  = (const float*)d_in[5];
    const float* phi_tb = (const float*)d_in[6];
    const float* Smat   = (const float*)d_in[7];
    const float* sb     = (const float*)d_in[8];
    float* out = (float*)d_out;

    char* ws = (char*)d_ws;
    ushort* wht  = (ushort*)(ws + OFF_WHT);
    ushort* wlt  = (ushort*)(ws + OFF_WLT);
    float2* psw  = (float2*)(ws + OFF_PSW);
    float2* pri  = (float2*)(ws + OFF_PRI);
    float* pmphi = (float*)(ws + OFF_PMPHI);
    float* psphi = (float*)(ws + OFF_PSPHI);
    float* pmpsi = (float*)(ws + OFF_PMPSI);
    float* pspsi = (float*)(ws + OFF_PSPSI);

    k0_pack<<<512, 64, 0, stream>>>(psi_r, psi_t, phi_r, phi_t, wht, wlt, psw);
    k1_gemm<<<ROWS / 128, 256, 0, stream>>>(x, (const uint*)wht, (const uint*)wlt, psw,
                                            psi_tb, phi_tb, pri, pmphi, psphi, pmpsi, pspsi);
    k5_out<<<B_, 512, 0, stream>>>(pri, pmphi, psphi, pmpsi, pspsi, Smat, sb, out);
}